// Round 1
// baseline (321.917 us; speedup 1.0000x reference)
//
#include <hip/hip_runtime.h>
#include <hip/hip_bf16.h>

// PatchLoss fused kernel for MI355X (gfx950).
//
// loss = (1/(B*T^2)) * sum_{b,t,u} w[b,t,u] * (z2[b,t] + z2[b,u] - 2*G[b,t,u])
//   w = exp(-sum_k gt_dT^2 / (2 sigma_k^2)),  G[b] = z_b z_b^T,  z2 = rowwise ||z||^2
//
// One block per b (256 blocks, 13 waves = 832 threads).
// Phase 1: batched Gram via mfma_f32_16x16x32_bf16, z staged f32->bf16 through
//          double-buffered LDS in K-slabs of 32. Each wave owns a 16x208 strip
//          (13 acc fragments). Exact f32 z2 accumulated during staging.
// Phase 2: stream gt_dT (float4/elem), w = __expf, combine with in-register G,
//          hierarchical reduce, one atomicAdd per block.
//
// Traffic: z 154MB + gt_dT 157MB read exactly once, ~0 writes. HBM floor 49us.

typedef __attribute__((ext_vector_type(8))) __bf16 bf16x8;
typedef __attribute__((ext_vector_type(4))) float f32x4;

#define NB   256          // batch
#define TT   196          // tokens
#define DD   768          // feature dim
#define TP   208          // padded T (13*16)
#define BK   32           // K-slab
#define NW   13           // waves per block
#define NTH  (NW * 64)    // 832 threads
#define NKS  (DD / BK)    // 24 K-steps

__device__ __forceinline__ bf16x8 pack8(const float4& a, const float4& b) {
    bf16x8 v;
    v[0] = (__bf16)a.x; v[1] = (__bf16)a.y; v[2] = (__bf16)a.z; v[3] = (__bf16)a.w;
    v[4] = (__bf16)b.x; v[5] = (__bf16)b.y; v[6] = (__bf16)b.z; v[7] = (__bf16)b.w;
    return v;
}

__device__ __forceinline__ float sq8(const float4& a, const float4& b) {
    return a.x*a.x + a.y*a.y + a.z*a.z + a.w*a.w
         + b.x*b.x + b.y*b.y + b.z*b.z + b.w*b.w;
}

__global__ __launch_bounds__(NTH)
void patch_loss_fused(const float* __restrict__ z,
                      const float* __restrict__ gt,
                      const float* __restrict__ sigma,
                      float* __restrict__ out)
{
    __shared__ __bf16 Zt[2][TP][BK];   // 2 x 13 KB staging buffers
    __shared__ float z2s[TP];
    __shared__ float red[NW];

    const int b    = blockIdx.x;
    const int tid  = threadIdx.x;
    const int lane = tid & 63;
    const int wid  = tid >> 6;

    // ---- staging assignment: thread covers (row = tid/4, 8 cols at (tid%4)*8)
    const int  srow = tid >> 2;          // 0..207
    const int  scol = (tid & 3) << 3;    // 0,8,16,24
    const bool srv  = srow < TT;
    const float* zrow = z + ((size_t)b * TT + srow) * DD + scol;

    f32x4 acc[NW];
#pragma unroll
    for (int j = 0; j < NW; ++j) acc[j] = (f32x4){0.f, 0.f, 0.f, 0.f};

    float z2p = 0.f;   // exact f32 partial of ||z_row||^2 over this thread's cols

    // ---- prologue: stage K-slab 0 into buffer 0
    {
        float4 r0 = make_float4(0.f,0.f,0.f,0.f), r1 = make_float4(0.f,0.f,0.f,0.f);
        if (srv) {
            r0 = *(const float4*)(zrow);
            r1 = *(const float4*)(zrow + 4);
        }
        z2p += sq8(r0, r1);
        *(bf16x8*)&Zt[0][srow][scol] = pack8(r0, r1);
    }

    // ---- MFMA fragment addressing
    // A frag (16x32): lane holds A[m = lane&15][k = 8*(lane>>4) + i]
    // B frag (32x16): lane holds B[k = 8*(lane>>4) + i][n = lane&15] = z[n][k]
    // -> both read 16B from row-major [row][32] bf16 slab at (row, 8*(lane>>4))
    const int arow = (wid << 4) + (lane & 15);
    const int koff = (lane >> 4) << 3;

    int cur = 0;
#pragma unroll 1
    for (int ks = 0; ks < NKS; ++ks) {
        __syncthreads();   // slab[cur] writes visible; prev reads of slab[cur^1] drained
        const bool more = (ks + 1) < NKS;

        float4 r0 = make_float4(0.f,0.f,0.f,0.f), r1 = make_float4(0.f,0.f,0.f,0.f);
        if (more && srv) {
            const float* p = zrow + (ks + 1) * BK;
            r0 = *(const float4*)(p);
            r1 = *(const float4*)(p + 4);
        }

        bf16x8 af = *(const bf16x8*)&Zt[cur][arow][koff];
#pragma unroll
        for (int j = 0; j < NW; ++j) {
            bf16x8 bfr = *(const bf16x8*)&Zt[cur][(j << 4) + (lane & 15)][koff];
            acc[j] = __builtin_amdgcn_mfma_f32_16x16x32_bf16(af, bfr, acc[j], 0, 0, 0);
        }

        if (more) {
            z2p += sq8(r0, r1);
            *(bf16x8*)&Zt[cur ^ 1][srow][scol] = pack8(r0, r1);
        }
        cur ^= 1;
    }

    // ---- finalize exact z2: reduce across the 4 threads sharing a row
    float zz = z2p + __shfl_xor(z2p, 1);
    zz += __shfl_xor(zz, 2);
    if ((tid & 3) == 0) z2s[srow] = srv ? zz : 0.f;
    __syncthreads();

    // ---- phase 2: stream gt_dT, fold with in-register Gram
    const float4 sg = *(const float4*)sigma;    // K = 4
    const float c0 = 0.5f / (sg.x * sg.x);
    const float c1 = 0.5f / (sg.y * sg.y);
    const float c2 = 0.5f / (sg.z * sg.z);
    const float c3 = 0.5f / (sg.w * sg.w);

    const int l15 = lane & 15;
    const int lq  = lane >> 4;

    // C/D layout (verified m89): col = lane&15, row = (lane>>4)*4 + reg
    int   trow[4];
    float z2t[4];
    size_t tbase[4];
#pragma unroll
    for (int r = 0; r < 4; ++r) {
        const int t = (wid << 4) + (lq << 2) + r;
        trow[r]  = t;
        z2t[r]   = z2s[t];                       // t < 208, zero-padded
        tbase[r] = ((size_t)b * TT + t) * TT;    // float4-element base (clamped use below)
    }

    const float4* gtp = (const float4*)gt;
    float lsum = 0.f;

#pragma unroll
    for (int j = 0; j < NW; ++j) {
        const int  u  = (j << 4) + l15;
        const bool uv = u < TT;
        const float z2u = z2s[u];

        float4 dv[4];
#pragma unroll
        for (int r = 0; r < 4; ++r) {
            const bool v = uv && (trow[r] < TT);
            dv[r] = v ? gtp[tbase[r] + u] : make_float4(0.f,0.f,0.f,0.f);
        }
#pragma unroll
        for (int r = 0; r < 4; ++r) {
            const bool v = uv && (trow[r] < TT);
            if (v) {
                const float s = dv[r].x*dv[r].x*c0 + dv[r].y*dv[r].y*c1
                              + dv[r].z*dv[r].z*c2 + dv[r].w*dv[r].w*c3;
                const float w = __expf(-s);
                lsum += w * (z2t[r] + z2u - 2.f * acc[j][r]);
            }
        }
    }

    // ---- reduction: wave shuffle -> LDS -> one atomic per block
#pragma unroll
    for (int off = 32; off > 0; off >>= 1) lsum += __shfl_xor(lsum, off);
    if (lane == 0) red[wid] = lsum;
    __syncthreads();
    if (tid == 0) {
        float s = 0.f;
#pragma unroll
        for (int w = 0; w < NW; ++w) s += red[w];
        const float scale = 1.0f / ((float)NB * (float)TT * (float)TT);
        atomicAdd(out, s * scale);
    }
}

extern "C" void kernel_launch(void* const* d_in, const int* in_sizes, int n_in,
                              void* d_out, int out_size, void* d_ws, size_t ws_size,
                              hipStream_t stream) {
    const float* z     = (const float*)d_in[0];
    const float* gt    = (const float*)d_in[1];
    const float* sigma = (const float*)d_in[2];
    float* out = (float*)d_out;

    hipMemsetAsync(out, 0, sizeof(float), stream);   // harness poisons d_out with 0xAA
    patch_loss_fused<<<dim3(NB), dim3(NTH), 0, stream>>>(z, gt, sigma, out);
}